// Round 1
// baseline (1529.773 us; speedup 1.0000x reference)
//
#include <hip/hip_runtime.h>

#define NN 100000
#define NE 1600000

// ---------------- degree ----------------
__global__ __launch_bounds__(256) void deg_kernel(const int* __restrict__ dst,
                                                  unsigned int* __restrict__ deg) {
    int e = blockIdx.x * 256 + threadIdx.x;
    if (e >= NE) return;
    atomicAdd(&deg[dst[e]], 1u);
}

__global__ __launch_bounds__(256) void dinv_kernel(const unsigned int* __restrict__ deg,
                                                   float* __restrict__ dinv) {
    int i = blockIdx.x * 256 + threadIdx.x;
    if (i >= NN) return;
    // self-loop adds 1 to degree; deg>0 always
    dinv[i] = rsqrtf((float)deg[i] + 1.0f);
}

// ---------------- embed MLP + hw1 = (h @ Wg1) * dinv ----------------
__global__ __launch_bounds__(256) void embed_kernel(
    const float* __restrict__ x,    // [N,6]
    const float* __restrict__ We1,  // [6,64]
    const float* __restrict__ be1,  // [64]
    const float* __restrict__ We2,  // [64,32]
    const float* __restrict__ be2,  // [32]
    const float* __restrict__ Wg1,  // [32,32]
    const float* __restrict__ dinv, // [N]
    float* __restrict__ hws,        // [N,32] out = (h@Wg1)*dinv
    float* __restrict__ acc)        // [N,32] zeroed here
{
    __shared__ float sWe1[6 * 64];
    __shared__ float sbe1[64];
    __shared__ float sWe2[64 * 32];
    __shared__ float sbe2[32];
    __shared__ float sWg1[32 * 32];
    for (int i = threadIdx.x; i < 6 * 64; i += 256) sWe1[i] = We1[i];
    for (int i = threadIdx.x; i < 64; i += 256) sbe1[i] = be1[i];
    for (int i = threadIdx.x; i < 64 * 32; i += 256) sWe2[i] = We2[i];
    for (int i = threadIdx.x; i < 32; i += 256) sbe2[i] = be2[i];
    for (int i = threadIdx.x; i < 32 * 32; i += 256) sWg1[i] = Wg1[i];
    __syncthreads();

    int node = blockIdx.x * 256 + threadIdx.x;
    if (node >= NN) return;

    float xv[6];
#pragma unroll
    for (int k = 0; k < 6; k++) xv[k] = x[node * 6 + k];

    float h1[64];
#pragma unroll
    for (int j = 0; j < 64; j++) {
        float a = sbe1[j];
#pragma unroll
        for (int k = 0; k < 6; k++) a += xv[k] * sWe1[k * 64 + j];
        h1[j] = tanhf(a);
    }

    float h[32];
#pragma unroll 4
    for (int j = 0; j < 32; j++) {
        float a = sbe2[j];
#pragma unroll
        for (int k = 0; k < 64; k++) a += h1[k] * sWe2[k * 32 + j];
        h[j] = tanhf(a);
    }

    float di = dinv[node];
    float* o = hws + (size_t)node * 32;
    float* az = acc + (size_t)node * 32;
#pragma unroll 4
    for (int j = 0; j < 32; j++) {
        float a = 0.f;
#pragma unroll
        for (int k = 0; k < 32; k++) a += h[k] * sWg1[k * 32 + j];
        o[j] = a * di;
        az[j] = 0.f;
    }
}

// ---------------- edge scatter: acc[dst] += hws[src] ----------------
__global__ __launch_bounds__(256) void scatter_kernel(
    const int* __restrict__ src, const int* __restrict__ dst,
    const float* __restrict__ hws, float* __restrict__ acc)
{
    long long t = (long long)blockIdx.x * 256 + threadIdx.x;
    int e = (int)(t >> 3);  // 8 threads per edge
    if (e >= NE) return;
    int part = ((int)t & 7) * 4;
    int s = src[e], d = dst[e];
    const float4 v = *reinterpret_cast<const float4*>(hws + (size_t)s * 32 + part);
    float* ap = acc + (size_t)d * 32 + part;
    atomicAdd(ap + 0, v.x);
    atomicAdd(ap + 1, v.y);
    atomicAdd(ap + 2, v.z);
    atomicAdd(ap + 3, v.w);
}

// ---------------- conv1 epilogue + hw2 = (relu(...) @ Wg2) * dinv ----------------
__global__ __launch_bounds__(256) void finish1_kernel(
    const float* __restrict__ bg1,  // [32]
    const float* __restrict__ Wg2,  // [32,32]
    const float* __restrict__ dinv,
    float* __restrict__ hws,  // in: hws1, out: hws2
    float* __restrict__ acc)  // in: scatter acc, re-zeroed
{
    __shared__ float sW[32 * 32];
    __shared__ float sb[32];
    for (int i = threadIdx.x; i < 32 * 32; i += 256) sW[i] = Wg2[i];
    if (threadIdx.x < 32) sb[threadIdx.x] = bg1[threadIdx.x];
    __syncthreads();

    int node = blockIdx.x * 256 + threadIdx.x;
    if (node >= NN) return;
    float di = dinv[node];
    float* hp = hws + (size_t)node * 32;
    float* ap = acc + (size_t)node * 32;
    float h[32];
#pragma unroll
    for (int j = 0; j < 32; j++) {
        float v = di * (ap[j] + hp[j]) + sb[j];
        h[j] = v > 0.f ? v : 0.f;
        ap[j] = 0.f;  // re-zero for scatter2
    }
#pragma unroll 4
    for (int j = 0; j < 32; j++) {
        float a = 0.f;
#pragma unroll
        for (int k = 0; k < 32; k++) a += h[k] * sW[k * 32 + j];
        hp[j] = a * di;
    }
}

// ---------------- conv2 epilogue + prediction MLP ----------------
__global__ __launch_bounds__(256) void final_kernel(
    const float* __restrict__ bg2,  // [32]
    const float* __restrict__ Wp1,  // [32,32]
    const float* __restrict__ bp1,  // [32]
    const float* __restrict__ Wp2,  // [32,1]
    const float* __restrict__ bp2,  // [1]
    const float* __restrict__ dinv,
    const float* __restrict__ hws,
    const float* __restrict__ acc,
    float* __restrict__ out)  // [N,1]
{
    __shared__ float sW1[32 * 32];
    __shared__ float sbg2[32];
    __shared__ float sb1[32];
    __shared__ float sW2[32];
    __shared__ float sb2;
    for (int i = threadIdx.x; i < 32 * 32; i += 256) sW1[i] = Wp1[i];
    if (threadIdx.x < 32) {
        sbg2[threadIdx.x] = bg2[threadIdx.x];
        sb1[threadIdx.x] = bp1[threadIdx.x];
        sW2[threadIdx.x] = Wp2[threadIdx.x];
    }
    if (threadIdx.x == 0) sb2 = bp2[0];
    __syncthreads();

    int node = blockIdx.x * 256 + threadIdx.x;
    if (node >= NN) return;
    float di = dinv[node];
    const float* hp = hws + (size_t)node * 32;
    const float* ap = acc + (size_t)node * 32;
    float h[32];
#pragma unroll
    for (int j = 0; j < 32; j++) {
        float v = di * (ap[j] + hp[j]) + sbg2[j];
        h[j] = v > 0.f ? v : 0.f;
    }
    float o = sb2;
#pragma unroll 4
    for (int j = 0; j < 32; j++) {
        float a = sb1[j];
#pragma unroll
        for (int k = 0; k < 32; k++) a += h[k] * sW1[k * 32 + j];
        o += tanhf(a) * sW2[j];
    }
    out[node] = tanhf(o);
}

extern "C" void kernel_launch(void* const* d_in, const int* in_sizes, int n_in,
                              void* d_out, int out_size, void* d_ws, size_t ws_size,
                              hipStream_t stream) {
    const float* x = (const float*)d_in[0];
    const int* edge = (const int*)d_in[1];  // [2, NE]
    const int* src = edge;
    const int* dst = edge + NE;
    const float* We1 = (const float*)d_in[2];
    const float* be1 = (const float*)d_in[3];
    const float* We2 = (const float*)d_in[4];
    const float* be2 = (const float*)d_in[5];
    const float* Wg1 = (const float*)d_in[6];
    const float* bg1 = (const float*)d_in[7];
    const float* Wg2 = (const float*)d_in[8];
    const float* bg2 = (const float*)d_in[9];
    const float* Wp1 = (const float*)d_in[10];
    const float* bp1 = (const float*)d_in[11];
    const float* Wp2 = (const float*)d_in[12];
    const float* bp2 = (const float*)d_in[13];
    float* out = (float*)d_out;

    // workspace layout (floats): deg[N] | dinv[N] | hws[32N] | acc[32N]
    unsigned int* deg = (unsigned int*)d_ws;
    float* dinv = (float*)d_ws + NN;
    float* hws = (float*)d_ws + 2 * NN;
    float* acc = (float*)d_ws + 2 * NN + 32 * NN;

    hipMemsetAsync(deg, 0, NN * sizeof(unsigned int), stream);

    int gridE = (NE + 255) / 256;
    int gridN = (NN + 255) / 256;
    int gridS = (NE * 8 + 255) / 256;

    deg_kernel<<<gridE, 256, 0, stream>>>(dst, deg);
    dinv_kernel<<<gridN, 256, 0, stream>>>(deg, dinv);
    embed_kernel<<<gridN, 256, 0, stream>>>(x, We1, be1, We2, be2, Wg1, dinv, hws, acc);
    scatter_kernel<<<gridS, 256, 0, stream>>>(src, dst, hws, acc);
    finish1_kernel<<<gridN, 256, 0, stream>>>(bg1, Wg2, dinv, hws, acc);
    scatter_kernel<<<gridS, 256, 0, stream>>>(src, dst, hws, acc);
    final_kernel<<<gridN, 256, 0, stream>>>(bg2, Wp1, bp1, Wp2, bp2, dinv, hws, acc, out);
}

// Round 2
// 545.818 us; speedup vs baseline: 2.8027x; 2.8027x over previous
//
#include <hip/hip_runtime.h>

#define NN 100000
#define NE 1600000
#define NBLK ((NN + 255) / 256)

// ---------------- degree ----------------
__global__ __launch_bounds__(256) void deg_kernel(const int* __restrict__ dst,
                                                  unsigned int* __restrict__ deg) {
    int e = blockIdx.x * 256 + threadIdx.x;
    if (e >= NE) return;
    atomicAdd(&deg[dst[e]], 1u);
}

__global__ __launch_bounds__(256) void dinv_kernel(const unsigned int* __restrict__ deg,
                                                   float* __restrict__ dinv) {
    int i = blockIdx.x * 256 + threadIdx.x;
    if (i >= NN) return;
    dinv[i] = rsqrtf((float)deg[i] + 1.0f);  // +1 = self-loop
}

// ---------------- prefix scan (3 kernels) ----------------
__global__ __launch_bounds__(256) void scan1_kernel(const unsigned int* __restrict__ deg,
                                                    unsigned int* __restrict__ excl,
                                                    unsigned int* __restrict__ bsum) {
    __shared__ unsigned int s[256];
    int i = blockIdx.x * 256 + threadIdx.x;
    unsigned int v = (i < NN) ? deg[i] : 0u;
    s[threadIdx.x] = v;
    __syncthreads();
    for (int off = 1; off < 256; off <<= 1) {
        unsigned int t = (threadIdx.x >= off) ? s[threadIdx.x - off] : 0u;
        __syncthreads();
        s[threadIdx.x] += t;
        __syncthreads();
    }
    if (i < NN) excl[i] = s[threadIdx.x] - v;
    if (threadIdx.x == 255) bsum[blockIdx.x] = s[255];
}

__global__ __launch_bounds__(512) void scan2_kernel(unsigned int* __restrict__ bsum) {
    __shared__ unsigned int s[512];
    unsigned int v = (threadIdx.x < NBLK) ? bsum[threadIdx.x] : 0u;
    s[threadIdx.x] = v;
    __syncthreads();
    for (int off = 1; off < 512; off <<= 1) {
        unsigned int t = (threadIdx.x >= off) ? s[threadIdx.x - off] : 0u;
        __syncthreads();
        s[threadIdx.x] += t;
        __syncthreads();
    }
    if (threadIdx.x < NBLK) bsum[threadIdx.x] = s[threadIdx.x] - v;  // exclusive
}

__global__ __launch_bounds__(256) void scan3_kernel(const unsigned int* __restrict__ excl,
                                                    const unsigned int* __restrict__ bsum,
                                                    unsigned int* __restrict__ row_off,
                                                    unsigned int* __restrict__ cursor) {
    int i = blockIdx.x * 256 + threadIdx.x;
    if (i >= NN) return;
    unsigned int r = excl[i] + bsum[blockIdx.x];
    row_off[i] = r;
    cursor[i] = r;
}

// ---------------- CSR fill ----------------
__global__ __launch_bounds__(256) void fill_kernel(const int* __restrict__ src,
                                                   const int* __restrict__ dst,
                                                   unsigned int* __restrict__ cursor,
                                                   int* __restrict__ csr) {
    int e = blockIdx.x * 256 + threadIdx.x;
    if (e >= NE) return;
    unsigned int pos = atomicAdd(&cursor[dst[e]], 1u);
    csr[pos] = src[e];
}

// ---------------- embed MLP + hw1 = (h @ Wg1) * dinv ----------------
__global__ __launch_bounds__(256) void embed_kernel(
    const float* __restrict__ x, const float* __restrict__ We1, const float* __restrict__ be1,
    const float* __restrict__ We2, const float* __restrict__ be2, const float* __restrict__ Wg1,
    const float* __restrict__ dinv, float* __restrict__ hws) {
    __shared__ float sWe1[6 * 64];
    __shared__ float sbe1[64];
    __shared__ float sWe2[64 * 32];
    __shared__ float sbe2[32];
    __shared__ float sWg1[32 * 32];
    for (int i = threadIdx.x; i < 6 * 64; i += 256) sWe1[i] = We1[i];
    for (int i = threadIdx.x; i < 64; i += 256) sbe1[i] = be1[i];
    for (int i = threadIdx.x; i < 64 * 32; i += 256) sWe2[i] = We2[i];
    for (int i = threadIdx.x; i < 32; i += 256) sbe2[i] = be2[i];
    for (int i = threadIdx.x; i < 32 * 32; i += 256) sWg1[i] = Wg1[i];
    __syncthreads();

    int node = blockIdx.x * 256 + threadIdx.x;
    if (node >= NN) return;

    float xv[6];
#pragma unroll
    for (int k = 0; k < 6; k++) xv[k] = x[node * 6 + k];

    float h1[64];
#pragma unroll
    for (int j = 0; j < 64; j++) {
        float a = sbe1[j];
#pragma unroll
        for (int k = 0; k < 6; k++) a += xv[k] * sWe1[k * 64 + j];
        h1[j] = tanhf(a);
    }

    float h[32];
#pragma unroll 4
    for (int j = 0; j < 32; j++) {
        float a = sbe2[j];
#pragma unroll
        for (int k = 0; k < 64; k++) a += h1[k] * sWe2[k * 32 + j];
        h[j] = tanhf(a);
    }

    float di = dinv[node];
    float* o = hws + (size_t)node * 32;
#pragma unroll 4
    for (int j = 0; j < 32; j++) {
        float a = 0.f;
#pragma unroll
        for (int k = 0; k < 32; k++) a += h[k] * sWg1[k * 32 + j];
        o[j] = a * di;
    }
}

// ---------------- gather: acc[n] = sum_{e in-edges of n} hws[src[e]] ----------------
__global__ __launch_bounds__(256) void gather_kernel(const int* __restrict__ csr,
                                                     const unsigned int* __restrict__ row_off,
                                                     const unsigned int* __restrict__ deg,
                                                     const float* __restrict__ hws,
                                                     float* __restrict__ acc) {
    int wid = (blockIdx.x * 256 + threadIdx.x) >> 6;  // one wave per node
    if (wid >= NN) return;
    int lane = threadIdx.x & 63;
    int half = lane >> 5;
    int f = lane & 31;
    unsigned int base = row_off[wid];
    unsigned int d = deg[wid];
    float a = 0.f;
    for (unsigned int k = half; k < d; k += 2) {
        int s = csr[base + k];
        a += hws[(size_t)s * 32 + f];
    }
    a += __shfl_down(a, 32);
    if (half == 0) acc[(size_t)wid * 32 + f] = a;
}

// ---------------- conv1 epilogue + hw2 = (relu(...) @ Wg2) * dinv ----------------
__global__ __launch_bounds__(256) void finish1_kernel(
    const float* __restrict__ bg1, const float* __restrict__ Wg2,
    const float* __restrict__ dinv, float* __restrict__ hws, const float* __restrict__ acc) {
    __shared__ float sW[32 * 32];
    __shared__ float sb[32];
    for (int i = threadIdx.x; i < 32 * 32; i += 256) sW[i] = Wg2[i];
    if (threadIdx.x < 32) sb[threadIdx.x] = bg1[threadIdx.x];
    __syncthreads();

    int node = blockIdx.x * 256 + threadIdx.x;
    if (node >= NN) return;
    float di = dinv[node];
    float* hp = hws + (size_t)node * 32;
    const float* ap = acc + (size_t)node * 32;
    float h[32];
#pragma unroll
    for (int j = 0; j < 32; j++) {
        float v = di * (ap[j] + hp[j]) + sb[j];
        h[j] = v > 0.f ? v : 0.f;
    }
#pragma unroll 4
    for (int j = 0; j < 32; j++) {
        float a = 0.f;
#pragma unroll
        for (int k = 0; k < 32; k++) a += h[k] * sW[k * 32 + j];
        hp[j] = a * di;
    }
}

// ---------------- conv2 epilogue + prediction MLP ----------------
__global__ __launch_bounds__(256) void final_kernel(
    const float* __restrict__ bg2, const float* __restrict__ Wp1, const float* __restrict__ bp1,
    const float* __restrict__ Wp2, const float* __restrict__ bp2, const float* __restrict__ dinv,
    const float* __restrict__ hws, const float* __restrict__ acc, float* __restrict__ out) {
    __shared__ float sW1[32 * 32];
    __shared__ float sbg2[32];
    __shared__ float sb1[32];
    __shared__ float sW2[32];
    __shared__ float sb2;
    for (int i = threadIdx.x; i < 32 * 32; i += 256) sW1[i] = Wp1[i];
    if (threadIdx.x < 32) {
        sbg2[threadIdx.x] = bg2[threadIdx.x];
        sb1[threadIdx.x] = bp1[threadIdx.x];
        sW2[threadIdx.x] = Wp2[threadIdx.x];
    }
    if (threadIdx.x == 0) sb2 = bp2[0];
    __syncthreads();

    int node = blockIdx.x * 256 + threadIdx.x;
    if (node >= NN) return;
    float di = dinv[node];
    const float* hp = hws + (size_t)node * 32;
    const float* ap = acc + (size_t)node * 32;
    float h[32];
#pragma unroll
    for (int j = 0; j < 32; j++) {
        float v = di * (ap[j] + hp[j]) + sbg2[j];
        h[j] = v > 0.f ? v : 0.f;
    }
    float o = sb2;
#pragma unroll 4
    for (int j = 0; j < 32; j++) {
        float a = sb1[j];
#pragma unroll
        for (int k = 0; k < 32; k++) a += h[k] * sW1[k * 32 + j];
        o += tanhf(a) * sW2[j];
    }
    out[node] = tanhf(o);
}

extern "C" void kernel_launch(void* const* d_in, const int* in_sizes, int n_in,
                              void* d_out, int out_size, void* d_ws, size_t ws_size,
                              hipStream_t stream) {
    const float* x = (const float*)d_in[0];
    const int* edge = (const int*)d_in[1];  // [2, NE] int32
    const int* src = edge;
    const int* dst = edge + NE;
    const float* We1 = (const float*)d_in[2];
    const float* be1 = (const float*)d_in[3];
    const float* We2 = (const float*)d_in[4];
    const float* be2 = (const float*)d_in[5];
    const float* Wg1 = (const float*)d_in[6];
    const float* bg1 = (const float*)d_in[7];
    const float* Wg2 = (const float*)d_in[8];
    const float* bg2 = (const float*)d_in[9];
    const float* Wp1 = (const float*)d_in[10];
    const float* bp1 = (const float*)d_in[11];
    const float* Wp2 = (const float*)d_in[12];
    const float* bp2 = (const float*)d_in[13];
    float* out = (float*)d_out;

    // workspace (4B units):
    // deg[N] | dinv[N] | hws[32N] | acc[32N] | excl[N] | row_off[N] | cursor[N] | bsum[1024] | csr[NE]
    unsigned int* deg = (unsigned int*)d_ws;
    float* dinv = (float*)d_ws + NN;
    float* hws = (float*)d_ws + 2 * NN;
    float* acc = (float*)d_ws + 2 * NN + 32 * NN;
    unsigned int* excl = (unsigned int*)d_ws + 66 * NN;
    unsigned int* row_off = (unsigned int*)d_ws + 67 * NN;
    unsigned int* cursor = (unsigned int*)d_ws + 68 * NN;
    unsigned int* bsum = (unsigned int*)d_ws + 69 * NN;
    int* csr = (int*)d_ws + 69 * NN + 1024;

    hipMemsetAsync(deg, 0, NN * sizeof(unsigned int), stream);

    int gridE = (NE + 255) / 256;
    int gridN = NBLK;
    int gridG = (NN * 64 + 255) / 256;  // one wave per node

    deg_kernel<<<gridE, 256, 0, stream>>>(dst, deg);
    dinv_kernel<<<gridN, 256, 0, stream>>>(deg, dinv);
    scan1_kernel<<<gridN, 256, 0, stream>>>(deg, excl, bsum);
    scan2_kernel<<<1, 512, 0, stream>>>(bsum);
    scan3_kernel<<<gridN, 256, 0, stream>>>(excl, bsum, row_off, cursor);
    fill_kernel<<<gridE, 256, 0, stream>>>(src, dst, cursor, csr);
    embed_kernel<<<gridN, 256, 0, stream>>>(x, We1, be1, We2, be2, Wg1, dinv, hws);
    gather_kernel<<<gridG, 256, 0, stream>>>(csr, row_off, deg, hws, acc);
    finish1_kernel<<<gridN, 256, 0, stream>>>(bg1, Wg2, dinv, hws, acc);
    gather_kernel<<<gridG, 256, 0, stream>>>(csr, row_off, deg, hws, acc);
    final_kernel<<<gridN, 256, 0, stream>>>(bg2, Wp1, bp1, Wp2, bp2, dinv, hws, acc, out);
}